// Round 8
// baseline (1316.290 us; speedup 1.0000x reference)
//
#include <hip/hip_runtime.h>
#include <hip/hip_bf16.h>

// HunyuanTopKGate: x[4096,4096] fp32, wg[64,4096] fp32 ->
//   combine_weights [T,E,C] fp32 ++ dispatch_mask [T,E,C] (as fp32 0/1)
// C = 2268 -> 4.76 GB output zero-fill (~765us at 6.2 TB/s) is the pole.
//
// Round 18: R17 falsified the tail-kernel theory (scatter/topk rewrite:
// nil). Ledger: dispatch-count (R15), x-ingest (R16), partial placement
// (R13), fill method (R14), fusion (R11/R12), tails (R17) -- ALL dead.
// Every round = fixed ~500us + fill(~765). Final falsification: the
// MINIMAL pipeline. 2 dispatches, zero partial traffic: nsplit=1 gemm
// blocks hold complete 64-expert logits in-register -> fuse softmax+top8
// into the gemm epilogue. Numerics kept bit-identical to the verified
// path: fp32 MFMA acc drained to f64 every 512 K (= old 8-slab order),
// same fp32-key/lower-expert tie-break, same k-ordered ssel sum ->
// selection bit-identical, weights differ only by f64 reassoc ulps.
// scatter2 is R17-verified. If total stays ~1260 -> fixed harness cost
// proven -> ROOFLINE. If it drops -> inter-dispatch chain was real.
//
// ws: idx8[4096*8] int | w8[4096*8] float   (256 KB)

#define TOK 4096
#define HID 4096
#define NE  64
#define NK  8

typedef __attribute__((ext_vector_type(8))) short short8;   // 8 bf16
typedef __attribute__((ext_vector_type(4))) float f32x4;

__device__ __forceinline__ short f2bf(float f) {
  __hip_bfloat16 h = __float2bfloat16(f);   // RNE
  return *reinterpret_cast<short*>(&h);
}
__device__ __forceinline__ float bf2f(short s) {
  unsigned u = ((unsigned)(unsigned short)s) << 16;
  return __uint_as_float(u);
}
__device__ __forceinline__ void cvt3(float f, short& s0, short& s1, short& s2) {
  s0 = f2bf(f);
  float r1 = f - bf2f(s0);
  s1 = f2bf(r1);
  float r2 = r1 - bf2f(s1);
  s2 = f2bf(r2);
}

// ---------------- 1. mega: {gemm+softmax+top8} blocks + fill blocks -------
// gemm blocks (bx < 64): 64 tokens x 64 experts x FULL K. R10-verbatim
// staging/MFMA; fp32 acc drained to f64 dacc every 512 K (8 drains) =
// bit-identical to the old per-slab partial accumulation. Epilogue:
// per-token softmax + top-8 via 16-lane-group butterflies (lane group
// q*16..+15 holds the token's 64 experts, 4 per lane).
// fill blocks (bx >= 64): R15-proven plain dwordx4 grid-stride stores.
__global__ __launch_bounds__(256) void mega(
    const float* __restrict__ x, const float* __restrict__ wg,
    int* __restrict__ idx8, float* __restrict__ w8, int nfill,
    float* __restrict__ out, int out_n) {
  const int bx  = blockIdx.x;
  const int tid = threadIdx.x;

  if (bx >= 64) {                       // ---- fill branch ----
    const int    fid    = bx - 64;
    const size_t n4     = ((size_t)(unsigned)out_n) >> 2;
    const size_t stride = (size_t)nfill * 256;
    f32x4* o4 = (f32x4*)out;
    const f32x4 z4 = (f32x4){0.f, 0.f, 0.f, 0.f};
    size_t i = (size_t)fid * 256 + tid;
    for (; i + 3 * stride < n4; i += 4 * stride) {
      o4[i]              = z4;
      o4[i + stride]     = z4;
      o4[i + 2 * stride] = z4;
      o4[i + 3 * stride] = z4;
    }
    for (; i < n4; i += stride) o4[i] = z4;
    if (fid == 0 && tid == 0)           // out_n % 4 == 0 -> empty, kept safe
      for (size_t i2 = n4 << 2; i2 < (size_t)(unsigned)out_n; ++i2) out[i2] = 0.f;
    return;
  }

  // ---- gemm branch (R10-verbatim staging/MFMA, full K, f64 drains) ----
  __shared__ __align__(16) short XA[3][64][72];   // 27.6 KB
  __shared__ __align__(16) short WB[3][64][72];   // 27.6 KB
  const int t0   = bx * 64;
  const int lane = tid & 63;
  const int w    = tid >> 6;
  const int m    = lane & 15;       // frag row/col within 16
  const int q    = lane >> 4;       // quad
  const int lrow = tid >> 2;        // staging: 4 threads per row
  const int lq   = tid & 3;         // 16 floats each

  f32x4 acc[4];
  double dacc[4][4];                // [nt][v] f64 logits
#pragma unroll
  for (int nt = 0; nt < 4; ++nt) {
    acc[nt] = (f32x4){0.f, 0.f, 0.f, 0.f};
#pragma unroll
    for (int v = 0; v < 4; ++v) dacc[nt][v] = 0.0;
  }

  for (int s = 0; s < HID; s += 64) {
    const int kk = s;
#pragma unroll
    for (int c = 0; c < 4; ++c) {
      const int col = lq * 16 + c * 4;
      float4 xv = *(const float4*)&x [(size_t)(t0 + lrow) * HID + kk + col];
      float4 wv = *(const float4*)&wg[(size_t)lrow * HID + kk + col];
      short4 p0, p1, p2;
      cvt3(xv.x, p0.x, p1.x, p2.x);  cvt3(xv.y, p0.y, p1.y, p2.y);
      cvt3(xv.z, p0.z, p1.z, p2.z);  cvt3(xv.w, p0.w, p1.w, p2.w);
      *(short4*)&XA[0][lrow][col] = p0;
      *(short4*)&XA[1][lrow][col] = p1;
      *(short4*)&XA[2][lrow][col] = p2;
      cvt3(wv.x, p0.x, p1.x, p2.x);  cvt3(wv.y, p0.y, p1.y, p2.y);
      cvt3(wv.z, p0.z, p1.z, p2.z);  cvt3(wv.w, p0.w, p1.w, p2.w);
      *(short4*)&WB[0][lrow][col] = p0;
      *(short4*)&WB[1][lrow][col] = p1;
      *(short4*)&WB[2][lrow][col] = p2;
    }
    __syncthreads();
#pragma unroll
    for (int kc = 0; kc < 64; kc += 32) {
      short8 a0 = *(const short8*)&XA[0][w * 16 + m][kc + q * 8];
      short8 a1 = *(const short8*)&XA[1][w * 16 + m][kc + q * 8];
      short8 a2 = *(const short8*)&XA[2][w * 16 + m][kc + q * 8];
#pragma unroll
      for (int nt = 0; nt < 4; ++nt) {
        short8 b0 = *(const short8*)&WB[0][nt * 16 + m][kc + q * 8];
        short8 b1 = *(const short8*)&WB[1][nt * 16 + m][kc + q * 8];
        short8 b2 = *(const short8*)&WB[2][nt * 16 + m][kc + q * 8];
        acc[nt] = __builtin_amdgcn_mfma_f32_16x16x32_bf16(a0, b0, acc[nt], 0, 0, 0);
        acc[nt] = __builtin_amdgcn_mfma_f32_16x16x32_bf16(a0, b1, acc[nt], 0, 0, 0);
        acc[nt] = __builtin_amdgcn_mfma_f32_16x16x32_bf16(a1, b0, acc[nt], 0, 0, 0);
        acc[nt] = __builtin_amdgcn_mfma_f32_16x16x32_bf16(a0, b2, acc[nt], 0, 0, 0);
        acc[nt] = __builtin_amdgcn_mfma_f32_16x16x32_bf16(a1, b1, acc[nt], 0, 0, 0);
        acc[nt] = __builtin_amdgcn_mfma_f32_16x16x32_bf16(a2, b0, acc[nt], 0, 0, 0);
      }
    }
    __syncthreads();
    // drain every 512 K: reproduces old 8-slab fp32->f64 sum order exactly
    if (((s >> 6) & 7) == 7) {
#pragma unroll
      for (int nt = 0; nt < 4; ++nt) {
#pragma unroll
        for (int v = 0; v < 4; ++v) dacc[nt][v] += (double)acc[nt][v];
        acc[nt] = (f32x4){0.f, 0.f, 0.f, 0.f};
      }
    }
  }

  // ---- fused softmax + top-8 epilogue ----
  // dacc[nt][v] = logit(token t0+w*16+q*4+v, expert nt*16+m); the 16
  // lanes sharing q hold one token's 64 experts (4 per lane).
#pragma unroll
  for (int v = 0; v < 4; ++v) {
    const int t = t0 + w * 16 + q * 4 + v;
    double M = dacc[0][v];
#pragma unroll
    for (int nt = 1; nt < 4; ++nt) M = dacc[nt][v] > M ? dacc[nt][v] : M;
#pragma unroll
    for (int off = 1; off < 16; off <<= 1) {
      double o = __shfl_xor(M, off);
      M = o > M ? o : M;
    }
    double g64[4], S = 0.0;
#pragma unroll
    for (int nt = 0; nt < 4; ++nt) { g64[nt] = exp(dacc[nt][v] - M); S += g64[nt]; }
#pragma unroll
    for (int off = 1; off < 16; off <<= 1) S += __shfl_xor(S, off);
    double gate[4]; float key[4];
#pragma unroll
    for (int nt = 0; nt < 4; ++nt) { gate[nt] = g64[nt] / S; key[nt] = (float)gate[nt]; }

    double ssel = 0.0, my_g = 0.0; int my_e = 0;
#pragma unroll
    for (int k = 0; k < NK; ++k) {
      float bk = key[0]; int bnt = 0;        // local argmax, tie -> lower nt (= lower e)
#pragma unroll
      for (int nt = 1; nt < 4; ++nt)
        if (key[nt] > bk) { bk = key[nt]; bnt = nt; }
      int    be = bnt * 16 + m;
      double bg = gate[bnt];
#pragma unroll
      for (int off = 1; off < 16; off <<= 1) {  // 16-lane argmax, tie -> lower e
        float  ok = __shfl_xor(bk, off);
        int    oe = __shfl_xor(be, off);
        double og = __shfl_xor(bg, off);
        if (ok > bk || (ok == bk && oe < be)) { bk = ok; be = oe; bg = og; }
      }
      ssel += bg;                                 // k-ordered, matches old
      if (m == (be & 15)) key[be >> 4] = -1.0f;   // knock out winner
      if (m == k) { my_e = be; my_g = bg; }       // lane k records winner k
    }
    const double eps = (double)1.1920929e-07f;
    double gs = ssel < eps ? eps : ssel;
    if (m < NK) {
      idx8[t * 8 + m] = my_e;
      w8 [t * 8 + m] = (float)(my_g / gs);
    }
  }
}

// ---------------- 2. scatter2: one pass + one LDS scan (R17-verified) -----
__global__ __launch_bounds__(1024) void scatter2(
    const int* __restrict__ idx8, const float* __restrict__ w8,
    float* __restrict__ out, int C) {
  const int e   = blockIdx.x;
  const int tid = threadIdx.x;
  __shared__ int sa[1024];
  __shared__ int sb[1024];

  const int base = tid * 32;           // item index base; k = base>>12 const
  const int k    = base >> 12;
  const int tbase = base & (TOK - 1);
  unsigned mask = 0u;
  int cnt = 0;
#pragma unroll 8
  for (int s = 0; s < 32; ++s) {
    if (idx8[(tbase + s) * 8 + k] == e) { mask |= (1u << s); ++cnt; }
  }

  sa[tid] = cnt;
  __syncthreads();
  int* src = sa; int* dst = sb;
  for (int off = 1; off < 1024; off <<= 1) {
    int v = src[tid];
    if (tid >= off) v += src[tid - off];
    dst[tid] = v;
    __syncthreads();
    int* tmp = src; src = dst; dst = tmp;
  }
  int c = src[tid] - cnt;              // exclusive prefix in flat order

  for (unsigned mm = mask; mm; mm &= (mm - 1)) {
    const int s = __builtin_ctz(mm);
    const int t = tbase + s;
    if (c < C) {
      const float wv = w8[t * 8 + k];
      const size_t off2 = ((size_t)t * NE + e) * (size_t)C + (size_t)c;
      out[off2] = wv;                          // combine_weights
      out[(size_t)TOK * NE * C + off2] = 1.0f; // dispatch_mask
    }
    ++c;
  }
}

extern "C" void kernel_launch(void* const* d_in, const int* in_sizes, int n_in,
                              void* d_out, int out_size, void* d_ws, size_t ws_size,
                              hipStream_t stream) {
  const float* x  = (const float*)d_in[0];   // [4096,4096]
  const float* wg = (const float*)d_in[1];   // [64,4096]
  float* out = (float*)d_out;

  const int C = out_size / (2 * TOK * NE);   // capacity from output size

  int*    idx8 = (int*)  d_ws;
  float*  w8   = (float*)((char*)d_ws + (size_t)NK * TOK * sizeof(int));

  const int nfill = 2048;            // plain-store fill blocks

  mega    <<<64 + nfill, 256, 0, stream>>>(x, wg, idx8, w8, nfill, out, out_size);
  scatter2<<<NE, 1024, 0, stream>>>(idx8, w8, out, C);
}